// Round 8
// baseline (118.284 us; speedup 1.0000x reference)
//
#include <hip/hip_runtime.h>
#include <hip/hip_bf16.h>

// ---------------------------------------------------------------------------
// Operand-swapped fully-fused MFMA kernel, zero h-LDS, spill-free.
// Round-8 restructure: kt-OUTER loop — weight fragments (10 GEMM2' + <=6
// GEMM1' b128 LDS reads per kt) loaded ONCE and reused by TWO jammed
// sample-tiles (2 passes x 2 tiles = 4 tiles of 16 samples per wave).
// Cuts DS-pipe pressure ~2x (was the saturated pipe: ~67% + 36% conflict
// cycles) and doubles per-wave ILP at fixed occupancy.
//   GEMM1': D[c][m] = (W|b)^T s^T ; value 1-term, location 3-term (hi/lo)
//   exchange: packed bf16 pairs, 8 bpermute + selects per stream
//   GEMM2': D[n][m]; each lane ends with (x,y,value) triples for 8
//           centroids of its own sample.
// Config: 256 threads, launch_bounds(256,2) (cap 256 VGPR — r6 lesson:
// never cap below need; r5/r7 needed 116, jam needs ~200).
// ---------------------------------------------------------------------------

typedef __attribute__((ext_vector_type(8))) short bf16x8;
typedef __attribute__((ext_vector_type(4))) float f32x4;

// short-index offsets inside ws / LDS
#define OFF_V1  0        // 7 half-tiles x 256 (value GEMM1' A, hi)
#define OFF_L1H 1792     // 7 half-tiles x 256 (loc GEMM1' A, hi)
#define OFF_L1L 3584     // 7 half-tiles x 256 (loc GEMM1' A, lo)
#define OFF_W2  5376     // 2 n-tiles x 4 kt x 512 (values GEMM2' A, hi)
#define OFF_W3H 9472     // 4 c-tiles x 4 kt x 512 (centroid GEMM2' A, hi)
#define OFF_W3L 17664    // same, lo
#define TOT_SHORTS 25856 // 51712 bytes

__device__ __forceinline__ short f2bf(float x) {
    union { float f; unsigned u; } v; v.f = x;
    unsigned r = v.u + 0x7FFFu + ((v.u >> 16) & 1u);   // RNE
    return (short)(r >> 16);
}
__device__ __forceinline__ float bf2f(short h) {
    union { unsigned u; float f; } v; v.u = ((unsigned)(unsigned short)h) << 16;
    return v.f;
}
// pack two f32 -> one u32 of 2 bf16 (RNE; lowers to v_cvt_pk_bf16_f32)
__device__ __forceinline__ unsigned cvt2(float a, float b) {
    union { __hip_bfloat162 h; unsigned u; } U;
    U.h = __float22bfloat162_rn(float2{a, b});
    return U.u;
}
__device__ __forceinline__ float lo16f(unsigned u) {
    union { unsigned u; float f; } V; V.u = u << 16; return V.f;
}
__device__ __forceinline__ float hi16f(unsigned u) {
    union { unsigned u; float f; } V; V.u = u & 0xFFFF0000u; return V.f;
}
__device__ __forceinline__ float tanh_fast(float x) {
    float e = __expf(2.f * x);
    return 1.f - 2.f / (e + 1.f);
}

// ---------------- prologue: build fragment-layout weights in ws ------------
__global__ __launch_bounds__(256) void prep_kernel(
    const float* __restrict__ W1, const float* __restrict__ b1,
    const float* __restrict__ W2, const float* __restrict__ b2,
    const float* __restrict__ L1, const float* __restrict__ bl1,
    const float* __restrict__ WL2, const float* __restrict__ bL2,
    short* __restrict__ ws)
{
    int idx = blockIdx.x * 256 + threadIdx.x;
    if (idx >= TOT_SHORTS) return;
    float val = 0.f;
    bool want_lo = false;

    if (idx < OFF_W2) {
        // GEMM1' A half-tiles: [region r][tile t][lane 0..31][j 0..7]
        int r = idx / 1792;              // 0 = W1(hi), 1 = L1(hi), 2 = L1(lo)
        int rem = idx - r * 1792;
        int t = rem >> 8, e = rem & 255;
        int ln = e >> 3, j = e & 7;      // ln 0..31
        int c = t * 16 + (ln & 15);      // hidden unit (row of A)
        int k = (ln >> 4) * 8 + j;       // 0..15 (real k: 0..10)
        const float* W  = (r == 0) ? W1 : L1;
        const float* bb = (r == 0) ? b1 : bl1;
        if (c < 100)       val = (k < 10) ? W[k * 100 + c] : ((k == 10) ? bb[c] : 0.f);
        else if (c == 100) val = (k == 10) ? 1.f : 0.f;    // generates h[100]=1 bias row
        want_lo = (r == 2);
    } else if (idx < OFF_W3H) {
        // GEMM2a' A: [T 0..1][kt 0..3][lane 0..63][j]
        int i2 = idx - OFF_W2;
        int T = i2 >> 11, kt = (i2 >> 9) & 3, e = i2 & 511;
        int ln = e >> 3, j = e & 7;
        int rho = ln & 15;
        int k = kt * 32 + (ln >> 4) * 8 + j;
        int n = 16 * T + 2 * (rho >> 2) + ((rho & 3) >> 1) * 8 + (rho & 1);
        if (n < 30) val = (k < 100) ? W2[k * 30 + n] : ((k == 100) ? b2[n] : 0.f);
    } else {
        // GEMM2b' A: [half h][t 0..3][kt][lane][j]
        int i3 = idx - OFF_W3H;
        want_lo = (i3 >= 8192); i3 &= 8191;
        int t = i3 >> 11, kt = (i3 >> 9) & 3, e = i3 & 511;
        int ln = e >> 3, j = e & 7;
        int rho = ln & 15;
        int k = kt * 32 + (ln >> 4) * 8 + j;
        int n = 8 * t + 2 * (rho >> 2) + ((rho & 3) >> 1);
        int d = rho & 1;
        if (n < 30) val = (k < 100) ? WL2[(n * 100 + k) * 2 + d]
                                    : ((k == 100) ? bL2[n * 2 + d] : 0.f);
    }
    short hi = f2bf(val);
    ws[idx] = want_lo ? f2bf(val - bf2f(hi)) : hi;
}

// ---------------- main fused kernel ----------------------------------------
__global__ __launch_bounds__(256, 2) void fused_kernel(
    const float* __restrict__ s, const float* __restrict__ a,
    const short* __restrict__ ws, float* __restrict__ out)
{
    __shared__ short lds[TOT_SHORTS];
    const int tid  = threadIdx.x;
    const int lane = tid & 63;
    const int wave = tid >> 6;
    const int m    = lane & 15;
    const int G    = lane >> 4;
    const int wgbase = blockIdx.x * 256;

    // stage ws -> LDS (identity copy, 16B chunks)
    {
        const int4* g4 = (const int4*)ws;
        int4* l4 = (int4*)lds;
        for (int i = tid; i < TOT_SHORTS / 8; i += 256) l4[i] = g4[i];
    }
    __syncthreads();

    const int srcA = m | ((2 * (G & 1)) << 4);
    const int srcB = srcA | 16;
    const bool hiTile = (G >> 1) != 0;     // this lane's k-range lives in tile t0+1

    const bf16x8 bz = {0, 0, 0, 0, 0, 0, 0, 0};
    const f32x4 fz = {0.f, 0.f, 0.f, 0.f};

    union Frag { bf16x8 v; unsigned u[4]; };

    // build s^T B-frag (hi + lo) for sample-tile base m0
    auto loadS = [&](int m0, bf16x8& shv, bf16x8& slv) {
        Frag H, L; H.v = bz; L.v = bz;
        const float2* p = (const float2*)(s + (size_t)(wgbase + m0 + m) * 10);
        if (G == 0) {
            float2 q0 = p[0], q1 = p[1], q2 = p[2], q3 = p[3];
            float qs[8] = {q0.x, q0.y, q1.x, q1.y, q2.x, q2.y, q3.x, q3.y};
            #pragma unroll
            for (int i = 0; i < 4; ++i) {
                unsigned uh = cvt2(qs[2 * i], qs[2 * i + 1]);
                H.u[i] = uh;
                L.u[i] = cvt2(qs[2 * i] - lo16f(uh), qs[2 * i + 1] - hi16f(uh));
            }
        } else if (G == 1) {
            float2 q4 = p[4];
            unsigned uh = cvt2(q4.x, q4.y);
            H.u[0] = uh;
            L.u[0] = cvt2(q4.x - lo16f(uh), q4.y - hi16f(uh));
            H.u[1] = 0x00003F80u;  // element 2: k = 10 -> 1.0 (bias row)
        }
        shv = H.v; slv = L.v;
    };

    // exchange: build GEMM2' B-frag for one kt from two tiles' pack words
    auto xch4 = [&](unsigned a0, unsigned a1, unsigned b0, unsigned b1,
                    bool hasT1) -> bf16x8 {
        unsigned e0 = (unsigned)__shfl((int)a0, srcA);
        unsigned e1 = (unsigned)__shfl((int)a1, srcA);
        unsigned e2 = (unsigned)__shfl((int)a0, srcB);
        unsigned e3 = (unsigned)__shfl((int)a1, srcB);
        unsigned f0 = 0, f1 = 0, f2 = 0, f3 = 0;
        if (hasT1) {
            f0 = (unsigned)__shfl((int)b0, srcA);
            f1 = (unsigned)__shfl((int)b1, srcA);
            f2 = (unsigned)__shfl((int)b0, srcB);
            f3 = (unsigned)__shfl((int)b1, srcB);
        }
        Frag U;
        U.u[0] = hiTile ? f0 : e0;
        U.u[1] = hiTile ? f1 : e1;
        U.u[2] = hiTile ? f2 : e2;
        U.u[3] = hiTile ? f3 : e3;
        return U.v;
    };

    // epilogue for one sample-tile
    auto epi = [&](const f32x4 (&DV)[2], const f32x4 (&DC)[4], int m0) {
        float2 av = ((const float2*)a)[wgbase + m0 + m];
        float num = 0.f, den = 0.f;
        #pragma unroll
        for (int t = 0; t < 4; ++t) {
            #pragma unroll
            for (int p = 0; p < 2; ++p) {
                float x = 5.f * tanh_fast(DC[t][2 * p]);
                float y = 5.f * tanh_fast(DC[t][2 * p + 1]);
                float ex = x - av.x, ey = y - av.y;
                float dist = sqrtf(fmaf(ex, ex, ey * ey));
                float wt = __expf(-3.f * dist);
                if (t == 3 && G == 3) wt = 0.f;      // n = 30,31 pad
                float v = (t < 2) ? DV[0][2 * t + p] : DV[1][2 * (t - 2) + p];
                num = fmaf(wt, v, num);
                den += wt;
            }
        }
        num += __shfl_xor(num, 16); den += __shfl_xor(den, 16);
        num += __shfl_xor(num, 32); den += __shfl_xor(den, 32);
        if (lane < 16) out[wgbase + m0 + m] = num / den;
    };

    for (int pass = 0; pass < 2; ++pass) {
        const int m0a = wave * 64 + pass * 32;
        const int m0b = m0a + 16;

        bf16x8 sh0, sl0, sh1, sl1;
        loadS(m0a, sh0, sl0);
        loadS(m0b, sh1, sl1);

        f32x4 DV0[2] = {fz, fz}, DC0[4] = {fz, fz, fz, fz};
        f32x4 DV1[2] = {fz, fz}, DC1[4] = {fz, fz, fz, fz};

        #pragma unroll
        for (int kt = 0; kt < 4; ++kt) {
            const bool h1 = (kt < 3);
            const int t0 = 2 * kt;

            // ---- GEMM1' weight frags for tiles t0 (and t0+1), once per kt ----
            bf16x8 aV0 = bz, aH0 = bz, aL0 = bz;
            bf16x8 aV1 = bz, aH1 = bz, aL1 = bz;
            if (lane < 32) {
                aV0 = *(const bf16x8*)(lds + OFF_V1  + t0 * 256 + lane * 8);
                aH0 = *(const bf16x8*)(lds + OFF_L1H + t0 * 256 + lane * 8);
                aL0 = *(const bf16x8*)(lds + OFF_L1L + t0 * 256 + lane * 8);
                if (h1) {
                    aV1 = *(const bf16x8*)(lds + OFF_V1  + (t0 + 1) * 256 + lane * 8);
                    aH1 = *(const bf16x8*)(lds + OFF_L1H + (t0 + 1) * 256 + lane * 8);
                    aL1 = *(const bf16x8*)(lds + OFF_L1L + (t0 + 1) * 256 + lane * 8);
                }
            }
            // ---- GEMM2' weight frags, once per kt, shared by both samples ----
            bf16x8 w2f[2], w3h[4], w3l[4];
            #pragma unroll
            for (int T = 0; T < 2; ++T)
                w2f[T] = *(const bf16x8*)(lds + OFF_W2 + (T * 4 + kt) * 512 + lane * 8);
            #pragma unroll
            for (int t = 0; t < 4; ++t) {
                w3h[t] = *(const bf16x8*)(lds + OFF_W3H + (t * 4 + kt) * 512 + lane * 8);
                w3l[t] = *(const bf16x8*)(lds + OFF_W3L + (t * 4 + kt) * 512 + lane * 8);
            }

            // GEMM1' one tile with given frags/sample -> packed pair words
            auto g1 = [&](const bf16x8& aV, const bf16x8& aH, const bf16x8& aL,
                          const bf16x8& sh, const bf16x8& sl,
                          unsigned& qv0, unsigned& qv1,
                          unsigned& qh0, unsigned& qh1,
                          unsigned& ql0, unsigned& ql1) {
                f32x4 dv = __builtin_amdgcn_mfma_f32_16x16x32_bf16(aV, sh, fz, 0, 0, 0);
                f32x4 dh = __builtin_amdgcn_mfma_f32_16x16x32_bf16(aH, sh, fz, 0, 0, 0);
                dh = __builtin_amdgcn_mfma_f32_16x16x32_bf16(aH, sl, dh, 0, 0, 0);
                dh = __builtin_amdgcn_mfma_f32_16x16x32_bf16(aL, sh, dh, 0, 0, 0);

                qv0 = cvt2(fmaxf(dv[0], 0.f), fmaxf(dv[1], 0.f));
                qv1 = cvt2(fmaxf(dv[2], 0.f), fmaxf(dv[3], 0.f));

                float h0 = fmaxf(dh[0], 0.f), h1f = fmaxf(dh[1], 0.f);
                float h2 = fmaxf(dh[2], 0.f), h3 = fmaxf(dh[3], 0.f);
                qh0 = cvt2(h0, h1f);
                qh1 = cvt2(h2, h3);
                ql0 = cvt2(h0 - lo16f(qh0), h1f - hi16f(qh0));
                ql1 = cvt2(h2 - lo16f(qh1), h3 - hi16f(qh1));
            };

            // one jammed sample-tile through this kt
            auto doSample = [&](const bf16x8& sh, const bf16x8& sl,
                                f32x4 (&DV)[2], f32x4 (&DC)[4]) {
                unsigned Av0, Av1, Ah0, Ah1, Al0, Al1;
                unsigned Bv0 = 0, Bv1 = 0, Bh0 = 0, Bh1 = 0, Bl0 = 0, Bl1 = 0;
                g1(aV0, aH0, aL0, sh, sl, Av0, Av1, Ah0, Ah1, Al0, Al1);
                if (h1) g1(aV1, aH1, aL1, sh, sl, Bv0, Bv1, Bh0, Bh1, Bl0, Bl1);

                bf16x8 bv = xch4(Av0, Av1, Bv0, Bv1, h1);
                bf16x8 bh = xch4(Ah0, Ah1, Bh0, Bh1, h1);
                bf16x8 bl = xch4(Al0, Al1, Bl0, Bl1, h1);

                #pragma unroll
                for (int T = 0; T < 2; ++T)
                    DV[T] = __builtin_amdgcn_mfma_f32_16x16x32_bf16(w2f[T], bv, DV[T], 0, 0, 0);
                #pragma unroll
                for (int t = 0; t < 4; ++t) {
                    DC[t] = __builtin_amdgcn_mfma_f32_16x16x32_bf16(w3h[t], bh, DC[t], 0, 0, 0);
                    DC[t] = __builtin_amdgcn_mfma_f32_16x16x32_bf16(w3h[t], bl, DC[t], 0, 0, 0);
                    DC[t] = __builtin_amdgcn_mfma_f32_16x16x32_bf16(w3l[t], bh, DC[t], 0, 0, 0);
                }
            };

            doSample(sh0, sl0, DV0, DC0);
            doSample(sh1, sl1, DV1, DC1);
        }

        epi(DV0, DC0, m0a);
        epi(DV1, DC1, m0b);
    }
}

extern "C" void kernel_launch(void* const* d_in, const int* in_sizes, int n_in,
                              void* d_out, int out_size, void* d_ws, size_t ws_size,
                              hipStream_t stream) {
    const float* s   = (const float*)d_in[0];
    const float* a   = (const float*)d_in[1];
    const float* W1  = (const float*)d_in[2];
    const float* b1  = (const float*)d_in[3];
    const float* W2  = (const float*)d_in[4];
    const float* b2  = (const float*)d_in[5];
    const float* L1  = (const float*)d_in[6];
    const float* bl1 = (const float*)d_in[7];
    const float* WL2 = (const float*)d_in[8];
    const float* bL2 = (const float*)d_in[9];
    float* out = (float*)d_out;
    short* ws  = (short*)d_ws;

    prep_kernel<<<(TOT_SHORTS + 255) / 256, 256, 0, stream>>>(
        W1, b1, W2, b2, L1, bl1, WL2, bL2, ws);

    int Btot = out_size;                 // 524288
    int grid = Btot / 256;               // 2048 WGs, 64 samples/wave
    fused_kernel<<<grid, 256, 0, stream>>>(s, a, ws, out);
}

// Round 9
// 88.045 us; speedup vs baseline: 1.3434x; 1.3434x over previous
//
#include <hip/hip_runtime.h>
#include <hip/hip_bf16.h>

// ---------------------------------------------------------------------------
// Round 9: LDS-FREE operand-swapped fused MFMA kernel.
// All weight fragments are read directly from global ws (51.7 KB, L2-resident,
// shared by every wave on the device) -> zero ds_read, zero LDS allocation,
// no __syncthreads. DS pipe carries only the bpermute exchange (inherent
// 2-way bank aliasing, ~free per m136). Jam-2 sample-tiles per kt so weight
// fragments are loaded once per 32 samples; GEMM1' frags die before the
// GEMM2' weight block loads (r8 spill lesson). kt loop kept rolled
// (#pragma unroll 1) to cap the register-hoisting window.
//   GEMM1': D[c][m] = (W|b)^T s^T ; value 1-term, location 3-term (hi/lo)
//   exchange: packed bf16 pairs, 8 bpermute + selects per stream
//   GEMM2': D[n][m]; each lane ends with (x,y,value) triples for 8
//           centroids of its own sample.
// ---------------------------------------------------------------------------

typedef __attribute__((ext_vector_type(8))) short bf16x8;
typedef __attribute__((ext_vector_type(4))) float f32x4;

// short-index offsets inside ws
#define OFF_V1  0        // 7 half-tiles x 256 (value GEMM1' A, hi)
#define OFF_L1H 1792     // 7 half-tiles x 256 (loc GEMM1' A, hi)
#define OFF_L1L 3584     // 7 half-tiles x 256 (loc GEMM1' A, lo)
#define OFF_W2  5376     // 2 n-tiles x 4 kt x 512 (values GEMM2' A, hi)
#define OFF_W3H 9472     // 4 c-tiles x 4 kt x 512 (centroid GEMM2' A, hi)
#define OFF_W3L 17664    // same, lo
#define TOT_SHORTS 25856 // 51712 bytes

__device__ __forceinline__ short f2bf(float x) {
    union { float f; unsigned u; } v; v.f = x;
    unsigned r = v.u + 0x7FFFu + ((v.u >> 16) & 1u);   // RNE
    return (short)(r >> 16);
}
__device__ __forceinline__ float bf2f(short h) {
    union { unsigned u; float f; } v; v.u = ((unsigned)(unsigned short)h) << 16;
    return v.f;
}
// pack two f32 -> one u32 of 2 bf16 (RNE; lowers to v_cvt_pk_bf16_f32)
__device__ __forceinline__ unsigned cvt2(float a, float b) {
    union { __hip_bfloat162 h; unsigned u; } U;
    U.h = __float22bfloat162_rn(float2{a, b});
    return U.u;
}
__device__ __forceinline__ float lo16f(unsigned u) {
    union { unsigned u; float f; } V; V.u = u << 16; return V.f;
}
__device__ __forceinline__ float hi16f(unsigned u) {
    union { unsigned u; float f; } V; V.u = u & 0xFFFF0000u; return V.f;
}
__device__ __forceinline__ float tanh_fast(float x) {
    float e = __expf(2.f * x);
    return 1.f - 2.f / (e + 1.f);
}

// ---------------- prologue: build fragment-layout weights in ws ------------
__global__ __launch_bounds__(256) void prep_kernel(
    const float* __restrict__ W1, const float* __restrict__ b1,
    const float* __restrict__ W2, const float* __restrict__ b2,
    const float* __restrict__ L1, const float* __restrict__ bl1,
    const float* __restrict__ WL2, const float* __restrict__ bL2,
    short* __restrict__ ws)
{
    int idx = blockIdx.x * 256 + threadIdx.x;
    if (idx >= TOT_SHORTS) return;
    float val = 0.f;
    bool want_lo = false;

    if (idx < OFF_W2) {
        // GEMM1' A half-tiles: [region r][tile t][lane 0..31][j 0..7]
        int r = idx / 1792;              // 0 = W1(hi), 1 = L1(hi), 2 = L1(lo)
        int rem = idx - r * 1792;
        int t = rem >> 8, e = rem & 255;
        int ln = e >> 3, j = e & 7;      // ln 0..31
        int c = t * 16 + (ln & 15);      // hidden unit (row of A)
        int k = (ln >> 4) * 8 + j;       // 0..15 (real k: 0..10)
        const float* W  = (r == 0) ? W1 : L1;
        const float* bb = (r == 0) ? b1 : bl1;
        if (c < 100)       val = (k < 10) ? W[k * 100 + c] : ((k == 10) ? bb[c] : 0.f);
        else if (c == 100) val = (k == 10) ? 1.f : 0.f;    // generates h[100]=1 bias row
        want_lo = (r == 2);
    } else if (idx < OFF_W3H) {
        // GEMM2a' A: [T 0..1][kt 0..3][lane 0..63][j]
        int i2 = idx - OFF_W2;
        int T = i2 >> 11, kt = (i2 >> 9) & 3, e = i2 & 511;
        int ln = e >> 3, j = e & 7;
        int rho = ln & 15;
        int k = kt * 32 + (ln >> 4) * 8 + j;
        int n = 16 * T + 2 * (rho >> 2) + ((rho & 3) >> 1) * 8 + (rho & 1);
        if (n < 30) val = (k < 100) ? W2[k * 30 + n] : ((k == 100) ? b2[n] : 0.f);
    } else {
        // GEMM2b' A: [half h][t 0..3][kt][lane][j]
        int i3 = idx - OFF_W3H;
        want_lo = (i3 >= 8192); i3 &= 8191;
        int t = i3 >> 11, kt = (i3 >> 9) & 3, e = i3 & 511;
        int ln = e >> 3, j = e & 7;
        int rho = ln & 15;
        int k = kt * 32 + (ln >> 4) * 8 + j;
        int n = 8 * t + 2 * (rho >> 2) + ((rho & 3) >> 1);
        int d = rho & 1;
        if (n < 30) val = (k < 100) ? WL2[(n * 100 + k) * 2 + d]
                                    : ((k == 100) ? bL2[n * 2 + d] : 0.f);
    }
    short hi = f2bf(val);
    ws[idx] = want_lo ? f2bf(val - bf2f(hi)) : hi;
}

// ---------------- main fused kernel (no LDS) -------------------------------
__global__ __launch_bounds__(256, 2) void fused_kernel(
    const float* __restrict__ s, const float* __restrict__ a,
    const short* __restrict__ ws, float* __restrict__ out)
{
    const int tid  = threadIdx.x;
    const int lane = tid & 63;
    const int wave = tid >> 6;
    const int m    = lane & 15;
    const int G    = lane >> 4;
    const int wgbase = blockIdx.x * 256;

    const int srcA = m | ((2 * (G & 1)) << 4);
    const int srcB = srcA | 16;
    const bool hiTile = (G >> 1) != 0;     // this lane's k-range lives in tile t0+1

    const bf16x8 bz = {0, 0, 0, 0, 0, 0, 0, 0};
    const f32x4 fz = {0.f, 0.f, 0.f, 0.f};

    union Frag { bf16x8 v; unsigned u[4]; };

    // build s^T B-frag (hi + lo) for sample-tile base m0
    auto loadS = [&](int m0, bf16x8& shv, bf16x8& slv) {
        Frag H, L; H.v = bz; L.v = bz;
        const float2* p = (const float2*)(s + (size_t)(wgbase + m0 + m) * 10);
        if (G == 0) {
            float2 q0 = p[0], q1 = p[1], q2 = p[2], q3 = p[3];
            float qs[8] = {q0.x, q0.y, q1.x, q1.y, q2.x, q2.y, q3.x, q3.y};
            #pragma unroll
            for (int i = 0; i < 4; ++i) {
                unsigned uh = cvt2(qs[2 * i], qs[2 * i + 1]);
                H.u[i] = uh;
                L.u[i] = cvt2(qs[2 * i] - lo16f(uh), qs[2 * i + 1] - hi16f(uh));
            }
        } else if (G == 1) {
            float2 q4 = p[4];
            unsigned uh = cvt2(q4.x, q4.y);
            H.u[0] = uh;
            L.u[0] = cvt2(q4.x - lo16f(uh), q4.y - hi16f(uh));
            H.u[1] = 0x00003F80u;  // element 2: k = 10 -> 1.0 (bias row)
        }
        shv = H.v; slv = L.v;
    };

    // GEMM1' one tile -> packed bf16 pair words (value, h-hi, h-lo)
    auto g1 = [&](const bf16x8& aV, const bf16x8& aH, const bf16x8& aL,
                  const bf16x8& sh, const bf16x8& sl,
                  unsigned& qv0, unsigned& qv1,
                  unsigned& qh0, unsigned& qh1,
                  unsigned& ql0, unsigned& ql1) {
        f32x4 dv = __builtin_amdgcn_mfma_f32_16x16x32_bf16(aV, sh, fz, 0, 0, 0);
        f32x4 dh = __builtin_amdgcn_mfma_f32_16x16x32_bf16(aH, sh, fz, 0, 0, 0);
        dh = __builtin_amdgcn_mfma_f32_16x16x32_bf16(aH, sl, dh, 0, 0, 0);
        dh = __builtin_amdgcn_mfma_f32_16x16x32_bf16(aL, sh, dh, 0, 0, 0);

        qv0 = cvt2(fmaxf(dv[0], 0.f), fmaxf(dv[1], 0.f));
        qv1 = cvt2(fmaxf(dv[2], 0.f), fmaxf(dv[3], 0.f));

        float h0 = fmaxf(dh[0], 0.f), h1f = fmaxf(dh[1], 0.f);
        float h2 = fmaxf(dh[2], 0.f), h3 = fmaxf(dh[3], 0.f);
        qh0 = cvt2(h0, h1f);
        qh1 = cvt2(h2, h3);
        ql0 = cvt2(h0 - lo16f(qh0), h1f - hi16f(qh0));
        ql1 = cvt2(h2 - lo16f(qh1), h3 - hi16f(qh1));
    };

    // exchange: build GEMM2' B-frag for one kt from two tiles' pack words
    auto xch4 = [&](unsigned a0, unsigned a1, unsigned b0, unsigned b1,
                    bool hasT1) -> bf16x8 {
        unsigned e0 = (unsigned)__shfl((int)a0, srcA);
        unsigned e1 = (unsigned)__shfl((int)a1, srcA);
        unsigned e2 = (unsigned)__shfl((int)a0, srcB);
        unsigned e3 = (unsigned)__shfl((int)a1, srcB);
        unsigned f0 = 0, f1 = 0, f2 = 0, f3 = 0;
        if (hasT1) {
            f0 = (unsigned)__shfl((int)b0, srcA);
            f1 = (unsigned)__shfl((int)b1, srcA);
            f2 = (unsigned)__shfl((int)b0, srcB);
            f3 = (unsigned)__shfl((int)b1, srcB);
        }
        Frag U;
        U.u[0] = hiTile ? f0 : e0;
        U.u[1] = hiTile ? f1 : e1;
        U.u[2] = hiTile ? f2 : e2;
        U.u[3] = hiTile ? f3 : e3;
        return U.v;
    };

    // epilogue for one sample-tile
    auto epi = [&](const f32x4 (&DV)[2], const f32x4 (&DC)[4], int m0) {
        float2 av = ((const float2*)a)[wgbase + m0 + m];
        float num = 0.f, den = 0.f;
        #pragma unroll
        for (int t = 0; t < 4; ++t) {
            #pragma unroll
            for (int p = 0; p < 2; ++p) {
                float x = 5.f * tanh_fast(DC[t][2 * p]);
                float y = 5.f * tanh_fast(DC[t][2 * p + 1]);
                float ex = x - av.x, ey = y - av.y;
                float dist = sqrtf(fmaf(ex, ex, ey * ey));
                float wt = __expf(-3.f * dist);
                if (t == 3 && G == 3) wt = 0.f;      // n = 30,31 pad
                float v = (t < 2) ? DV[0][2 * t + p] : DV[1][2 * (t - 2) + p];
                num = fmaf(wt, v, num);
                den += wt;
            }
        }
        num += __shfl_xor(num, 16); den += __shfl_xor(den, 16);
        num += __shfl_xor(num, 32); den += __shfl_xor(den, 32);
        if (lane < 16) out[wgbase + m0 + m] = num / den;
    };

    for (int pass = 0; pass < 2; ++pass) {
        const int m0a = wave * 64 + pass * 32;
        const int m0b = m0a + 16;

        bf16x8 sh0, sl0, sh1, sl1;
        loadS(m0a, sh0, sl0);
        loadS(m0b, sh1, sl1);

        f32x4 DV0[2] = {fz, fz}, DC0[4] = {fz, fz, fz, fz};
        f32x4 DV1[2] = {fz, fz}, DC1[4] = {fz, fz, fz, fz};

        #pragma unroll 1
        for (int kt = 0; kt < 4; ++kt) {
            const bool h1 = (kt < 3);
            const int t0 = 2 * kt;

            // ---- phase 1: GEMM1' A-frags (global, L2) + both samples' g1 ----
            bf16x8 aV0 = bz, aH0 = bz, aL0 = bz;
            bf16x8 aV1 = bz, aH1 = bz, aL1 = bz;
            if (lane < 32) {
                aV0 = *(const bf16x8*)(ws + OFF_V1  + t0 * 256 + lane * 8);
                aH0 = *(const bf16x8*)(ws + OFF_L1H + t0 * 256 + lane * 8);
                aL0 = *(const bf16x8*)(ws + OFF_L1L + t0 * 256 + lane * 8);
                if (h1) {
                    aV1 = *(const bf16x8*)(ws + OFF_V1  + (t0 + 1) * 256 + lane * 8);
                    aH1 = *(const bf16x8*)(ws + OFF_L1H + (t0 + 1) * 256 + lane * 8);
                    aL1 = *(const bf16x8*)(ws + OFF_L1L + (t0 + 1) * 256 + lane * 8);
                }
            }
            unsigned Av0, Av1, Ah0, Ah1, Al0, Al1;          // sample0, tile t0
            unsigned Bv0 = 0, Bv1 = 0, Bh0 = 0, Bh1 = 0, Bl0 = 0, Bl1 = 0;
            unsigned Cv0, Cv1, Ch0, Ch1, Cl0, Cl1;          // sample1, tile t0
            unsigned Dv0 = 0, Dv1 = 0, Dh0 = 0, Dh1 = 0, Dl0 = 0, Dl1 = 0;
            g1(aV0, aH0, aL0, sh0, sl0, Av0, Av1, Ah0, Ah1, Al0, Al1);
            g1(aV0, aH0, aL0, sh1, sl1, Cv0, Cv1, Ch0, Ch1, Cl0, Cl1);
            if (h1) {
                g1(aV1, aH1, aL1, sh0, sl0, Bv0, Bv1, Bh0, Bh1, Bl0, Bl1);
                g1(aV1, aH1, aL1, sh1, sl1, Dv0, Dv1, Dh0, Dh1, Dl0, Dl1);
            }
            // GEMM1' frags dead here.

            // ---- phase 2: exchange (bpermute crossbar, no LDS memory) -------
            bf16x8 bv0 = xch4(Av0, Av1, Bv0, Bv1, h1);
            bf16x8 bh0 = xch4(Ah0, Ah1, Bh0, Bh1, h1);
            bf16x8 bl0 = xch4(Al0, Al1, Bl0, Bl1, h1);
            bf16x8 bv1 = xch4(Cv0, Cv1, Dv0, Dv1, h1);
            bf16x8 bh1 = xch4(Ch0, Ch1, Dh0, Dh1, h1);
            bf16x8 bl1 = xch4(Cl0, Cl1, Dl0, Dl1, h1);

            // ---- phase 3: GEMM2' weight frags (global, L2) + consume --------
            bf16x8 w2f[2], w3h[4], w3l[4];
            #pragma unroll
            for (int T = 0; T < 2; ++T)
                w2f[T] = *(const bf16x8*)(ws + OFF_W2 + (T * 4 + kt) * 512 + lane * 8);
            #pragma unroll
            for (int t = 0; t < 4; ++t) {
                w3h[t] = *(const bf16x8*)(ws + OFF_W3H + (t * 4 + kt) * 512 + lane * 8);
                w3l[t] = *(const bf16x8*)(ws + OFF_W3L + (t * 4 + kt) * 512 + lane * 8);
            }
            #pragma unroll
            for (int T = 0; T < 2; ++T) {
                DV0[T] = __builtin_amdgcn_mfma_f32_16x16x32_bf16(w2f[T], bv0, DV0[T], 0, 0, 0);
                DV1[T] = __builtin_amdgcn_mfma_f32_16x16x32_bf16(w2f[T], bv1, DV1[T], 0, 0, 0);
            }
            #pragma unroll
            for (int t = 0; t < 4; ++t) {
                DC0[t] = __builtin_amdgcn_mfma_f32_16x16x32_bf16(w3h[t], bh0, DC0[t], 0, 0, 0);
                DC0[t] = __builtin_amdgcn_mfma_f32_16x16x32_bf16(w3h[t], bl0, DC0[t], 0, 0, 0);
                DC0[t] = __builtin_amdgcn_mfma_f32_16x16x32_bf16(w3l[t], bh0, DC0[t], 0, 0, 0);
                DC1[t] = __builtin_amdgcn_mfma_f32_16x16x32_bf16(w3h[t], bh1, DC1[t], 0, 0, 0);
                DC1[t] = __builtin_amdgcn_mfma_f32_16x16x32_bf16(w3h[t], bl1, DC1[t], 0, 0, 0);
                DC1[t] = __builtin_amdgcn_mfma_f32_16x16x32_bf16(w3l[t], bh1, DC1[t], 0, 0, 0);
            }
        }

        epi(DV0, DC0, m0a);
        epi(DV1, DC1, m0b);
    }
}

extern "C" void kernel_launch(void* const* d_in, const int* in_sizes, int n_in,
                              void* d_out, int out_size, void* d_ws, size_t ws_size,
                              hipStream_t stream) {
    const float* s   = (const float*)d_in[0];
    const float* a   = (const float*)d_in[1];
    const float* W1  = (const float*)d_in[2];
    const float* b1  = (const float*)d_in[3];
    const float* W2  = (const float*)d_in[4];
    const float* b2  = (const float*)d_in[5];
    const float* L1  = (const float*)d_in[6];
    const float* bl1 = (const float*)d_in[7];
    const float* WL2 = (const float*)d_in[8];
    const float* bL2 = (const float*)d_in[9];
    float* out = (float*)d_out;
    short* ws  = (short*)d_ws;

    prep_kernel<<<(TOT_SHORTS + 255) / 256, 256, 0, stream>>>(
        W1, b1, W2, b2, L1, bl1, WL2, bL2, ws);

    int Btot = out_size;                 // 524288
    int grid = Btot / 256;               // 2048 WGs, 64 samples/wave
    fused_kernel<<<grid, 256, 0, stream>>>(s, a, ws, out);
}

// Round 10
// 87.698 us; speedup vs baseline: 1.3488x; 1.0040x over previous
//
#include <hip/hip_runtime.h>
#include <hip/hip_bf16.h>

// ---------------------------------------------------------------------------
// Round 10: LDS-free operand-swapped fused MFMA kernel, 32 samples/wave.
// r9 structure (global-L2 weight frags, jam-2 sample-tiles, kt-outer,
// phase-ordered to keep GEMM1' frags dead before GEMM2' frags load) with
// the 2-pass loop removed: each wave does ONE pass of 32 samples and the
// grid doubles to 4096 WGs. Per-sample weight traffic unchanged; per-wave
// critical path halves; 2x schedulable WGs/CU to hide dep-chain stalls.
//   GEMM1': D[c][m] = (W|b)^T s^T ; value 1-term, location 3-term (hi/lo)
//   exchange: packed bf16 pairs, 8 bpermute + 4 selects per stream
//   GEMM2': D[n][m]; each lane ends with (x,y,value) triples for 8
//           centroids of its own sample.
// ---------------------------------------------------------------------------

typedef __attribute__((ext_vector_type(8))) short bf16x8;
typedef __attribute__((ext_vector_type(4))) float f32x4;

// short-index offsets inside ws
#define OFF_V1  0        // 7 half-tiles x 256 (value GEMM1' A, hi)
#define OFF_L1H 1792     // 7 half-tiles x 256 (loc GEMM1' A, hi)
#define OFF_L1L 3584     // 7 half-tiles x 256 (loc GEMM1' A, lo)
#define OFF_W2  5376     // 2 n-tiles x 4 kt x 512 (values GEMM2' A, hi)
#define OFF_W3H 9472     // 4 c-tiles x 4 kt x 512 (centroid GEMM2' A, hi)
#define OFF_W3L 17664    // same, lo
#define TOT_SHORTS 25856 // 51712 bytes

__device__ __forceinline__ short f2bf(float x) {
    union { float f; unsigned u; } v; v.f = x;
    unsigned r = v.u + 0x7FFFu + ((v.u >> 16) & 1u);   // RNE
    return (short)(r >> 16);
}
__device__ __forceinline__ float bf2f(short h) {
    union { unsigned u; float f; } v; v.u = ((unsigned)(unsigned short)h) << 16;
    return v.f;
}
// pack two f32 -> one u32 of 2 bf16 (RNE; lowers to v_cvt_pk_bf16_f32)
__device__ __forceinline__ unsigned cvt2(float a, float b) {
    union { __hip_bfloat162 h; unsigned u; } U;
    U.h = __float22bfloat162_rn(float2{a, b});
    return U.u;
}
__device__ __forceinline__ float lo16f(unsigned u) {
    union { unsigned u; float f; } V; V.u = u << 16; return V.f;
}
__device__ __forceinline__ float hi16f(unsigned u) {
    union { unsigned u; float f; } V; V.u = u & 0xFFFF0000u; return V.f;
}
__device__ __forceinline__ float tanh_fast(float x) {
    float e = __expf(2.f * x);
    return 1.f - 2.f / (e + 1.f);
}

// ---------------- prologue: build fragment-layout weights in ws ------------
__global__ __launch_bounds__(256) void prep_kernel(
    const float* __restrict__ W1, const float* __restrict__ b1,
    const float* __restrict__ W2, const float* __restrict__ b2,
    const float* __restrict__ L1, const float* __restrict__ bl1,
    const float* __restrict__ WL2, const float* __restrict__ bL2,
    short* __restrict__ ws)
{
    int idx = blockIdx.x * 256 + threadIdx.x;
    if (idx >= TOT_SHORTS) return;
    float val = 0.f;
    bool want_lo = false;

    if (idx < OFF_W2) {
        // GEMM1' A half-tiles: [region r][tile t][lane 0..31][j 0..7]
        int r = idx / 1792;              // 0 = W1(hi), 1 = L1(hi), 2 = L1(lo)
        int rem = idx - r * 1792;
        int t = rem >> 8, e = rem & 255;
        int ln = e >> 3, j = e & 7;      // ln 0..31
        int c = t * 16 + (ln & 15);      // hidden unit (row of A)
        int k = (ln >> 4) * 8 + j;       // 0..15 (real k: 0..10)
        const float* W  = (r == 0) ? W1 : L1;
        const float* bb = (r == 0) ? b1 : bl1;
        if (c < 100)       val = (k < 10) ? W[k * 100 + c] : ((k == 10) ? bb[c] : 0.f);
        else if (c == 100) val = (k == 10) ? 1.f : 0.f;    // generates h[100]=1 bias row
        want_lo = (r == 2);
    } else if (idx < OFF_W3H) {
        // GEMM2a' A: [T 0..1][kt 0..3][lane 0..63][j]
        int i2 = idx - OFF_W2;
        int T = i2 >> 11, kt = (i2 >> 9) & 3, e = i2 & 511;
        int ln = e >> 3, j = e & 7;
        int rho = ln & 15;
        int k = kt * 32 + (ln >> 4) * 8 + j;
        int n = 16 * T + 2 * (rho >> 2) + ((rho & 3) >> 1) * 8 + (rho & 1);
        if (n < 30) val = (k < 100) ? W2[k * 30 + n] : ((k == 100) ? b2[n] : 0.f);
    } else {
        // GEMM2b' A: [half h][t 0..3][kt][lane][j]
        int i3 = idx - OFF_W3H;
        want_lo = (i3 >= 8192); i3 &= 8191;
        int t = i3 >> 11, kt = (i3 >> 9) & 3, e = i3 & 511;
        int ln = e >> 3, j = e & 7;
        int rho = ln & 15;
        int k = kt * 32 + (ln >> 4) * 8 + j;
        int n = 8 * t + 2 * (rho >> 2) + ((rho & 3) >> 1);
        int d = rho & 1;
        if (n < 30) val = (k < 100) ? WL2[(n * 100 + k) * 2 + d]
                                    : ((k == 100) ? bL2[n * 2 + d] : 0.f);
    }
    short hi = f2bf(val);
    ws[idx] = want_lo ? f2bf(val - bf2f(hi)) : hi;
}

// ---------------- main fused kernel (no LDS, 32 samples/wave) --------------
__global__ __launch_bounds__(256, 2) void fused_kernel(
    const float* __restrict__ s, const float* __restrict__ a,
    const short* __restrict__ ws, float* __restrict__ out)
{
    const int tid  = threadIdx.x;
    const int lane = tid & 63;
    const int wave = tid >> 6;
    const int m    = lane & 15;
    const int G    = lane >> 4;
    const int wgbase = blockIdx.x * 128;   // 4 waves x 32 samples

    const int srcA = m | ((2 * (G & 1)) << 4);
    const int srcB = srcA | 16;
    const bool hiTile = (G >> 1) != 0;     // this lane's k-range lives in tile t0+1

    const bf16x8 bz = {0, 0, 0, 0, 0, 0, 0, 0};
    const f32x4 fz = {0.f, 0.f, 0.f, 0.f};

    union Frag { bf16x8 v; unsigned u[4]; };

    // build s^T B-frag (hi + lo) for sample-tile base m0
    auto loadS = [&](int m0, bf16x8& shv, bf16x8& slv) {
        Frag H, L; H.v = bz; L.v = bz;
        const float2* p = (const float2*)(s + (size_t)(wgbase + m0 + m) * 10);
        if (G == 0) {
            float2 q0 = p[0], q1 = p[1], q2 = p[2], q3 = p[3];
            float qs[8] = {q0.x, q0.y, q1.x, q1.y, q2.x, q2.y, q3.x, q3.y};
            #pragma unroll
            for (int i = 0; i < 4; ++i) {
                unsigned uh = cvt2(qs[2 * i], qs[2 * i + 1]);
                H.u[i] = uh;
                L.u[i] = cvt2(qs[2 * i] - lo16f(uh), qs[2 * i + 1] - hi16f(uh));
            }
        } else if (G == 1) {
            float2 q4 = p[4];
            unsigned uh = cvt2(q4.x, q4.y);
            H.u[0] = uh;
            L.u[0] = cvt2(q4.x - lo16f(uh), q4.y - hi16f(uh));
            H.u[1] = 0x00003F80u;  // element 2: k = 10 -> 1.0 (bias row)
        }
        shv = H.v; slv = L.v;
    };

    // GEMM1' one tile -> packed bf16 pair words (value, h-hi, h-lo)
    auto g1 = [&](const bf16x8& aV, const bf16x8& aH, const bf16x8& aL,
                  const bf16x8& sh, const bf16x8& sl,
                  unsigned& qv0, unsigned& qv1,
                  unsigned& qh0, unsigned& qh1,
                  unsigned& ql0, unsigned& ql1) {
        f32x4 dv = __builtin_amdgcn_mfma_f32_16x16x32_bf16(aV, sh, fz, 0, 0, 0);
        f32x4 dh = __builtin_amdgcn_mfma_f32_16x16x32_bf16(aH, sh, fz, 0, 0, 0);
        dh = __builtin_amdgcn_mfma_f32_16x16x32_bf16(aH, sl, dh, 0, 0, 0);
        dh = __builtin_amdgcn_mfma_f32_16x16x32_bf16(aL, sh, dh, 0, 0, 0);

        qv0 = cvt2(fmaxf(dv[0], 0.f), fmaxf(dv[1], 0.f));
        qv1 = cvt2(fmaxf(dv[2], 0.f), fmaxf(dv[3], 0.f));

        float h0 = fmaxf(dh[0], 0.f), h1f = fmaxf(dh[1], 0.f);
        float h2 = fmaxf(dh[2], 0.f), h3 = fmaxf(dh[3], 0.f);
        qh0 = cvt2(h0, h1f);
        qh1 = cvt2(h2, h3);
        ql0 = cvt2(h0 - lo16f(qh0), h1f - hi16f(qh0));
        ql1 = cvt2(h2 - lo16f(qh1), h3 - hi16f(qh1));
    };

    // exchange: build GEMM2' B-frag for one kt from two tiles' pack words
    auto xch4 = [&](unsigned a0, unsigned a1, unsigned b0, unsigned b1,
                    bool hasT1) -> bf16x8 {
        unsigned e0 = (unsigned)__shfl((int)a0, srcA);
        unsigned e1 = (unsigned)__shfl((int)a1, srcA);
        unsigned e2 = (unsigned)__shfl((int)a0, srcB);
        unsigned e3 = (unsigned)__shfl((int)a1, srcB);
        unsigned f0 = 0, f1 = 0, f2 = 0, f3 = 0;
        if (hasT1) {
            f0 = (unsigned)__shfl((int)b0, srcA);
            f1 = (unsigned)__shfl((int)b1, srcA);
            f2 = (unsigned)__shfl((int)b0, srcB);
            f3 = (unsigned)__shfl((int)b1, srcB);
        }
        Frag U;
        U.u[0] = hiTile ? f0 : e0;
        U.u[1] = hiTile ? f1 : e1;
        U.u[2] = hiTile ? f2 : e2;
        U.u[3] = hiTile ? f3 : e3;
        return U.v;
    };

    // epilogue for one sample-tile
    auto epi = [&](const f32x4 (&DV)[2], const f32x4 (&DC)[4], int m0) {
        float2 av = ((const float2*)a)[wgbase + m0 + m];
        float num = 0.f, den = 0.f;
        #pragma unroll
        for (int t = 0; t < 4; ++t) {
            #pragma unroll
            for (int p = 0; p < 2; ++p) {
                float x = 5.f * tanh_fast(DC[t][2 * p]);
                float y = 5.f * tanh_fast(DC[t][2 * p + 1]);
                float ex = x - av.x, ey = y - av.y;
                float dist = sqrtf(fmaf(ex, ex, ey * ey));
                float wt = __expf(-3.f * dist);
                if (t == 3 && G == 3) wt = 0.f;      // n = 30,31 pad
                float v = (t < 2) ? DV[0][2 * t + p] : DV[1][2 * (t - 2) + p];
                num = fmaf(wt, v, num);
                den += wt;
            }
        }
        num += __shfl_xor(num, 16); den += __shfl_xor(den, 16);
        num += __shfl_xor(num, 32); den += __shfl_xor(den, 32);
        if (lane < 16) out[wgbase + m0 + m] = num / den;
    };

    const int m0a = wave * 32;
    const int m0b = m0a + 16;

    bf16x8 sh0, sl0, sh1, sl1;
    loadS(m0a, sh0, sl0);
    loadS(m0b, sh1, sl1);

    f32x4 DV0[2] = {fz, fz}, DC0[4] = {fz, fz, fz, fz};
    f32x4 DV1[2] = {fz, fz}, DC1[4] = {fz, fz, fz, fz};

    #pragma unroll 1
    for (int kt = 0; kt < 4; ++kt) {
        const bool h1 = (kt < 3);
        const int t0 = 2 * kt;

        // ---- phase 1: GEMM1' A-frags (global, L2) + both samples' g1 ----
        bf16x8 aV0 = bz, aH0 = bz, aL0 = bz;
        bf16x8 aV1 = bz, aH1 = bz, aL1 = bz;
        if (lane < 32) {
            aV0 = *(const bf16x8*)(ws + OFF_V1  + t0 * 256 + lane * 8);
            aH0 = *(const bf16x8*)(ws + OFF_L1H + t0 * 256 + lane * 8);
            aL0 = *(const bf16x8*)(ws + OFF_L1L + t0 * 256 + lane * 8);
            if (h1) {
                aV1 = *(const bf16x8*)(ws + OFF_V1  + (t0 + 1) * 256 + lane * 8);
                aH1 = *(const bf16x8*)(ws + OFF_L1H + (t0 + 1) * 256 + lane * 8);
                aL1 = *(const bf16x8*)(ws + OFF_L1L + (t0 + 1) * 256 + lane * 8);
            }
        }
        unsigned Av0, Av1, Ah0, Ah1, Al0, Al1;          // sample0, tile t0
        unsigned Bv0 = 0, Bv1 = 0, Bh0 = 0, Bh1 = 0, Bl0 = 0, Bl1 = 0;
        unsigned Cv0, Cv1, Ch0, Ch1, Cl0, Cl1;          // sample1, tile t0
        unsigned Dv0 = 0, Dv1 = 0, Dh0 = 0, Dh1 = 0, Dl0 = 0, Dl1 = 0;
        g1(aV0, aH0, aL0, sh0, sl0, Av0, Av1, Ah0, Ah1, Al0, Al1);
        g1(aV0, aH0, aL0, sh1, sl1, Cv0, Cv1, Ch0, Ch1, Cl0, Cl1);
        if (h1) {
            g1(aV1, aH1, aL1, sh0, sl0, Bv0, Bv1, Bh0, Bh1, Bl0, Bl1);
            g1(aV1, aH1, aL1, sh1, sl1, Dv0, Dv1, Dh0, Dh1, Dl0, Dl1);
        }
        // GEMM1' frags dead here.

        // ---- phase 2: exchange (bpermute crossbar, no LDS memory) -------
        bf16x8 bv0 = xch4(Av0, Av1, Bv0, Bv1, h1);
        bf16x8 bh0 = xch4(Ah0, Ah1, Bh0, Bh1, h1);
        bf16x8 bl0 = xch4(Al0, Al1, Bl0, Bl1, h1);
        bf16x8 bv1 = xch4(Cv0, Cv1, Dv0, Dv1, h1);
        bf16x8 bh1 = xch4(Ch0, Ch1, Dh0, Dh1, h1);
        bf16x8 bl1 = xch4(Cl0, Cl1, Dl0, Dl1, h1);

        // ---- phase 3: GEMM2' weight frags (global, L2) + consume --------
        bf16x8 w2f[2], w3h[4], w3l[4];
        #pragma unroll
        for (int T = 0; T < 2; ++T)
            w2f[T] = *(const bf16x8*)(ws + OFF_W2 + (T * 4 + kt) * 512 + lane * 8);
        #pragma unroll
        for (int t = 0; t < 4; ++t) {
            w3h[t] = *(const bf16x8*)(ws + OFF_W3H + (t * 4 + kt) * 512 + lane * 8);
            w3l[t] = *(const bf16x8*)(ws + OFF_W3L + (t * 4 + kt) * 512 + lane * 8);
        }
        #pragma unroll
        for (int T = 0; T < 2; ++T) {
            DV0[T] = __builtin_amdgcn_mfma_f32_16x16x32_bf16(w2f[T], bv0, DV0[T], 0, 0, 0);
            DV1[T] = __builtin_amdgcn_mfma_f32_16x16x32_bf16(w2f[T], bv1, DV1[T], 0, 0, 0);
        }
        #pragma unroll
        for (int t = 0; t < 4; ++t) {
            DC0[t] = __builtin_amdgcn_mfma_f32_16x16x32_bf16(w3h[t], bh0, DC0[t], 0, 0, 0);
            DC0[t] = __builtin_amdgcn_mfma_f32_16x16x32_bf16(w3h[t], bl0, DC0[t], 0, 0, 0);
            DC0[t] = __builtin_amdgcn_mfma_f32_16x16x32_bf16(w3l[t], bh0, DC0[t], 0, 0, 0);
            DC1[t] = __builtin_amdgcn_mfma_f32_16x16x32_bf16(w3h[t], bh1, DC1[t], 0, 0, 0);
            DC1[t] = __builtin_amdgcn_mfma_f32_16x16x32_bf16(w3h[t], bl1, DC1[t], 0, 0, 0);
            DC1[t] = __builtin_amdgcn_mfma_f32_16x16x32_bf16(w3l[t], bh1, DC1[t], 0, 0, 0);
        }
    }

    epi(DV0, DC0, m0a);
    epi(DV1, DC1, m0b);
}

extern "C" void kernel_launch(void* const* d_in, const int* in_sizes, int n_in,
                              void* d_out, int out_size, void* d_ws, size_t ws_size,
                              hipStream_t stream) {
    const float* s   = (const float*)d_in[0];
    const float* a   = (const float*)d_in[1];
    const float* W1  = (const float*)d_in[2];
    const float* b1  = (const float*)d_in[3];
    const float* W2  = (const float*)d_in[4];
    const float* b2  = (const float*)d_in[5];
    const float* L1  = (const float*)d_in[6];
    const float* bl1 = (const float*)d_in[7];
    const float* WL2 = (const float*)d_in[8];
    const float* bL2 = (const float*)d_in[9];
    float* out = (float*)d_out;
    short* ws  = (short*)d_ws;

    prep_kernel<<<(TOT_SHORTS + 255) / 256, 256, 0, stream>>>(
        W1, b1, W2, b2, L1, bl1, WL2, bL2, ws);

    int Btot = out_size;                 // 524288
    int grid = Btot / 128;               // 4096 WGs, 32 samples/wave
    fused_kernel<<<grid, 256, 0, stream>>>(s, a, ws, out);
}